// Round 1
// baseline (389.034 us; speedup 1.0000x reference)
//
#include <hip/hip_runtime.h>
#include <string.h>

#define SEQ 4096
#define DIM 512
#define NH  8
#define HD  64

typedef __attribute__((ext_vector_type(4))) float  f32x4;
typedef __attribute__((ext_vector_type(8))) short  bf16x8;
typedef __attribute__((ext_vector_type(4))) short  s16x4;

// f32 -> bf16 round-to-nearest-even (finite inputs only)
__device__ __forceinline__ unsigned short f2bf(float f){
    unsigned int u = __float_as_uint(f);
    u = (u + 0x7fffu + ((u >> 16) & 1u)) >> 16;
    return (unsigned short)u;
}

__device__ __forceinline__ bf16x8 cvt8(f32x4 lo, f32x4 hi){
    bf16x8 r;
    r[0]=(short)f2bf(lo[0]); r[1]=(short)f2bf(lo[1]);
    r[2]=(short)f2bf(lo[2]); r[3]=(short)f2bf(lo[3]);
    r[4]=(short)f2bf(hi[0]); r[5]=(short)f2bf(hi[1]);
    r[6]=(short)f2bf(hi[2]); r[7]=(short)f2bf(hi[3]);
    return r;
}

// load 8 contiguous f32 and convert to a bf16 MFMA fragment
__device__ __forceinline__ bf16x8 load8f(const float* p){
    f32x4 lo = *(const f32x4*)p;
    f32x4 hi = *(const f32x4*)(p+4);
    return cvt8(lo, hi);
}

// Schraudolph fast exp, matching the reference's fastexp_gist in f32
__device__ __forceinline__ float fexp(float x){
    float t = 12102203.171338f * x + 1064986823.0f;
    t = (t < 8388608.0f) ? 0.0f : ((t > 2139095040.0f) ? 2139095040.0f : t);
    return __int_as_float((int)t);
}

// ---------------------------------------------------------------------------
// Kernel 1: fused Q/K/V projections.  Y = x @ W^T + b, bf16 outputs.
// z = blockIdx.z selects W (0=Q, 1=K, 2=V). V is written TRANSPOSED:
// Vt[outdim][seq], so attention's PV B-fragments read contiguous keys.
// Per wave: 32 rows x 64 cols output tile via 16x16x32 bf16 MFMA.
// ---------------------------------------------------------------------------
__global__ __launch_bounds__(256) void proj_qkv_kernel(
    const float* __restrict__ x,
    const float* __restrict__ Wq, const float* __restrict__ bq,
    const float* __restrict__ Wk, const float* __restrict__ bk,
    const float* __restrict__ Wv, const float* __restrict__ bv,
    unsigned short* __restrict__ Qb, unsigned short* __restrict__ Kb,
    unsigned short* __restrict__ Vt)
{
    const int z = blockIdx.z;
    const float* W  = (z==0) ? Wq : ((z==1) ? Wk : Wv);
    const float* bb = (z==0) ? bq : ((z==1) ? bk : bv);
    const int wv  = threadIdx.x >> 6;
    const int l   = threadIdx.x & 63;
    const int g   = l >> 4;
    const int l15 = l & 15;
    const int r0  = blockIdx.x * 128 + wv * 32;
    const int c0  = blockIdx.y * 64;

    f32x4 acc[2][4];
    #pragma unroll
    for(int s=0;s<2;s++)
        #pragma unroll
        for(int d=0;d<4;d++) acc[s][d] = (f32x4){0.f,0.f,0.f,0.f};

    for(int kt=0; kt<DIM; kt+=32){
        bf16x8 a[2];
        #pragma unroll
        for(int s=0;s<2;s++)
            a[s] = load8f(x + (size_t)(r0+s*16+l15)*DIM + kt + g*8);
        #pragma unroll
        for(int d=0;d<4;d++){
            bf16x8 b = load8f(W + (size_t)(c0+d*16+l15)*DIM + kt + g*8);
            #pragma unroll
            for(int s=0;s<2;s++)
                acc[s][d] = __builtin_amdgcn_mfma_f32_16x16x32_bf16(a[s], b, acc[s][d], 0,0,0);
        }
    }

    #pragma unroll
    for(int d=0;d<4;d++){
        float bias = bb[c0 + d*16 + l15];
        #pragma unroll
        for(int s=0;s<2;s++){
            if(z == 2){
                // transposed write: 4 consecutive seq positions per lane -> 8B store
                s16x4 pk;
                #pragma unroll
                for(int r=0;r<4;r++) pk[r] = (short)f2bf(acc[s][d][r] + bias);
                *(s16x4*)(Vt + (size_t)(c0+d*16+l15)*SEQ + r0 + s*16 + g*4) = pk;
            } else {
                unsigned short* o = (z==0) ? Qb : Kb;
                #pragma unroll
                for(int r=0;r<4;r++)
                    o[(size_t)(r0+s*16+g*4+r)*DIM + c0 + d*16 + l15] = f2bf(acc[s][d][r] + bias);
            }
        }
    }
}

// ---------------------------------------------------------------------------
// Kernel 2: fused two-pass attention (exact softmax w.r.t. reference math).
// One block = 4 independent waves, each owning 32 query rows of one head.
// Pass A: row max of scaled scores. Pass B: recompute scores (bit-identical),
// p = fastexp(s - m), accumulate P@V (via per-wave LDS transpose of P) and
// row sums; epilogue divides. No __syncthreads(): waves are independent,
// cross-lane LDS traffic is fenced with wave-synchronous lgkmcnt(0).
// ---------------------------------------------------------------------------
__global__ __launch_bounds__(256) void attn_kernel(
    const unsigned short* __restrict__ Qb,
    const unsigned short* __restrict__ Kb,
    const unsigned short* __restrict__ Vt,
    unsigned short* __restrict__ Ab,
    float scaling)
{
    __shared__ __align__(16) unsigned short plds[4][32][72]; // 72 = 64 + pad (bank spread)
    const int wv  = threadIdx.x >> 6;
    const int l   = threadIdx.x & 63;
    const int g   = l >> 4;
    const int l15 = l & 15;
    const int h   = blockIdx.y;
    const int r0  = blockIdx.x * 128 + wv * 32;

    // Q fragments held in registers for the whole kernel: 32 rows x 64 dims
    bf16x8 aq[2][2];
    #pragma unroll
    for(int s=0;s<2;s++)
        #pragma unroll
        for(int kh=0;kh<2;kh++)
            aq[s][kh] = *(const bf16x8*)(Qb + (size_t)(r0+s*16+l15)*DIM + h*HD + kh*32 + g*8);

    // ---- pass A: row maxima ----
    float mx[2][4];
    #pragma unroll
    for(int s=0;s<2;s++){ mx[s][0]=mx[s][1]=mx[s][2]=mx[s][3]=-3.0e38f; }

    for(int k0=0; k0<SEQ; k0+=64){
        #pragma unroll
        for(int ks=0;ks<4;ks++){
            const unsigned short* kp = Kb + (size_t)(k0+ks*16+l15)*DIM + h*HD + g*8;
            bf16x8 b0 = *(const bf16x8*)kp;
            bf16x8 b1 = *(const bf16x8*)(kp + 32);
            #pragma unroll
            for(int s=0;s<2;s++){
                f32x4 acc = (f32x4){0.f,0.f,0.f,0.f};
                acc = __builtin_amdgcn_mfma_f32_16x16x32_bf16(aq[s][0], b0, acc, 0,0,0);
                acc = __builtin_amdgcn_mfma_f32_16x16x32_bf16(aq[s][1], b1, acc, 0,0,0);
                #pragma unroll
                for(int r=0;r<4;r++) mx[s][r] = fmaxf(mx[s][r], acc[r]*scaling);
            }
        }
    }
    // reduce max across the 16 lanes sharing each row group
    #pragma unroll
    for(int off=1; off<16; off<<=1)
        #pragma unroll
        for(int s=0;s<2;s++)
            #pragma unroll
            for(int r=0;r<4;r++)
                mx[s][r] = fmaxf(mx[s][r], __shfl_xor(mx[s][r], off, 64));

    // ---- pass B: p = fe(s-m), accumulate num & den ----
    float den[2][4];
    #pragma unroll
    for(int s=0;s<2;s++){ den[s][0]=den[s][1]=den[s][2]=den[s][3]=0.f; }
    f32x4 oacc[2][4];
    #pragma unroll
    for(int s=0;s<2;s++)
        #pragma unroll
        for(int d=0;d<4;d++) oacc[s][d] = (f32x4){0.f,0.f,0.f,0.f};

    for(int k0=0; k0<SEQ; k0+=64){
        #pragma unroll
        for(int ks=0;ks<4;ks++){
            const unsigned short* kp = Kb + (size_t)(k0+ks*16+l15)*DIM + h*HD + g*8;
            bf16x8 b0 = *(const bf16x8*)kp;
            bf16x8 b1 = *(const bf16x8*)(kp + 32);
            #pragma unroll
            for(int s=0;s<2;s++){
                f32x4 acc = (f32x4){0.f,0.f,0.f,0.f};
                acc = __builtin_amdgcn_mfma_f32_16x16x32_bf16(aq[s][0], b0, acc, 0,0,0);
                acc = __builtin_amdgcn_mfma_f32_16x16x32_bf16(aq[s][1], b1, acc, 0,0,0);
                #pragma unroll
                for(int r=0;r<4;r++){
                    float p = fexp(acc[r]*scaling - mx[s][r]);
                    den[s][r] += p;
                    plds[wv][s*16 + g*4 + r][ks*16 + l15] = f2bf(p);
                }
            }
        }
        // wave-synchronous fence: all ds_writes visible before cross-lane reads
        __builtin_amdgcn_sched_barrier(0);
        asm volatile("s_waitcnt lgkmcnt(0)" ::: "memory");
        __builtin_amdgcn_sched_barrier(0);

        #pragma unroll
        for(int ks2=0; ks2<2; ks2++){
            bf16x8 pa[2];
            #pragma unroll
            for(int s=0;s<2;s++)
                pa[s] = *(const bf16x8*)&plds[wv][s*16 + l15][ks2*32 + g*8];
            #pragma unroll
            for(int d=0;d<4;d++){
                bf16x8 bv_ = *(const bf16x8*)(Vt + (size_t)(h*HD + d*16 + l15)*SEQ + k0 + ks2*32 + g*8);
                #pragma unroll
                for(int s=0;s<2;s++)
                    oacc[s][d] = __builtin_amdgcn_mfma_f32_16x16x32_bf16(pa[s], bv_, oacc[s][d], 0,0,0);
            }
        }
        // fence so next iteration's P writes can't hoist above these reads
        __builtin_amdgcn_sched_barrier(0);
        asm volatile("s_waitcnt lgkmcnt(0)" ::: "memory");
        __builtin_amdgcn_sched_barrier(0);
    }

    #pragma unroll
    for(int off=1; off<16; off<<=1)
        #pragma unroll
        for(int s=0;s<2;s++)
            #pragma unroll
            for(int r=0;r<4;r++)
                den[s][r] += __shfl_xor(den[s][r], off, 64);

    #pragma unroll
    for(int s=0;s<2;s++)
        #pragma unroll
        for(int d=0;d<4;d++)
            #pragma unroll
            for(int r=0;r<4;r++){
                float o = oacc[s][d][r] / den[s][r];
                Ab[(size_t)(r0+s*16+g*4+r)*DIM + h*HD + d*16 + l15] = f2bf(o);
            }
}

// ---------------------------------------------------------------------------
// Kernel 3: output projection. out = attn @ Wout^T, f32 output.
// ---------------------------------------------------------------------------
__global__ __launch_bounds__(256) void proj_out_kernel(
    const unsigned short* __restrict__ Ab,
    const float* __restrict__ Wout,
    float* __restrict__ out)
{
    const int wv  = threadIdx.x >> 6;
    const int l   = threadIdx.x & 63;
    const int g   = l >> 4;
    const int l15 = l & 15;
    const int r0  = blockIdx.x * 128 + wv * 32;
    const int c0  = blockIdx.y * 64;

    f32x4 acc[2][4];
    #pragma unroll
    for(int s=0;s<2;s++)
        #pragma unroll
        for(int d=0;d<4;d++) acc[s][d] = (f32x4){0.f,0.f,0.f,0.f};

    for(int kt=0; kt<DIM; kt+=32){
        bf16x8 a[2];
        #pragma unroll
        for(int s=0;s<2;s++)
            a[s] = *(const bf16x8*)(Ab + (size_t)(r0+s*16+l15)*DIM + kt + g*8);
        #pragma unroll
        for(int d=0;d<4;d++){
            bf16x8 b = load8f(Wout + (size_t)(c0+d*16+l15)*DIM + kt + g*8);
            #pragma unroll
            for(int s=0;s<2;s++)
                acc[s][d] = __builtin_amdgcn_mfma_f32_16x16x32_bf16(a[s], b, acc[s][d], 0,0,0);
        }
    }

    #pragma unroll
    for(int s=0;s<2;s++)
        #pragma unroll
        for(int d=0;d<4;d++)
            #pragma unroll
            for(int r=0;r<4;r++)
                out[(size_t)(r0+s*16+g*4+r)*DIM + c0 + d*16 + l15] = acc[s][d][r];
}

// ---------------------------------------------------------------------------
extern "C" void kernel_launch(void* const* d_in, const int* in_sizes, int n_in,
                              void* d_out, int out_size, void* d_ws, size_t ws_size,
                              hipStream_t stream)
{
    const float* x    = (const float*)d_in[0];
    const float* Wq   = (const float*)d_in[1];
    const float* bq   = (const float*)d_in[2];
    const float* Wk   = (const float*)d_in[3];
    const float* bk   = (const float*)d_in[4];
    const float* Wv   = (const float*)d_in[5];
    const float* bv   = (const float*)d_in[6];
    const float* Wout = (const float*)d_in[7];
    float* out = (float*)d_out;

    unsigned short* Qb = (unsigned short*)d_ws;          // [SEQ][DIM] bf16
    unsigned short* Kb = Qb + (size_t)SEQ*DIM;           // [SEQ][DIM] bf16
    unsigned short* Vt = Kb + (size_t)SEQ*DIM;           // [DIM][SEQ] bf16 (transposed)
    unsigned short* Ab = Vt + (size_t)SEQ*DIM;           // [SEQ][DIM] bf16

    // quake fast inverse sqrt of HEAD_DIM, replicating the numpy f32 ops exactly
    float xx = 64.0f;
    float x2 = xx * 0.5f;
    int ii; memcpy(&ii, &xx, 4);
    ii = 1597463007 - (ii >> 1);
    float y; memcpy(&y, &ii, 4);
    y = y * (1.5f - x2 * y * y);
    const float scaling = y;

    proj_qkv_kernel<<<dim3(SEQ/128, DIM/64, 3), 256, 0, stream>>>(
        x, Wq, bq, Wk, bk, Wv, bv, Qb, Kb, Vt);
    attn_kernel<<<dim3(SEQ/128, NH), 256, 0, stream>>>(Qb, Kb, Vt, Ab, scaling);
    proj_out_kernel<<<dim3(SEQ/128, DIM/64), 256, 0, stream>>>(Ab, Wout, out);
}

// Round 2
// 234.256 us; speedup vs baseline: 1.6607x; 1.6607x over previous
//
#include <hip/hip_runtime.h>
#include <hip/hip_bf16.h>
#include <string.h>

#define SEQ 4096
#define DIM 512
#define NH  8
#define HD  64

typedef __attribute__((ext_vector_type(4))) float  f32x4;
typedef __attribute__((ext_vector_type(8))) short  bf16x8;
typedef __attribute__((ext_vector_type(4))) short  s16x4;

// f32 -> bf16 via hardware convert (RNE on gfx950), 1-2 VALU ops
__device__ __forceinline__ unsigned short f2bfh(float f){
    union { __hip_bfloat16 h; unsigned short u; } cv;
    cv.h = __float2bfloat16(f);
    return cv.u;
}

__device__ __forceinline__ bf16x8 cvt8(f32x4 lo, f32x4 hi){
    bf16x8 r;
    r[0]=(short)f2bfh(lo[0]); r[1]=(short)f2bfh(lo[1]);
    r[2]=(short)f2bfh(lo[2]); r[3]=(short)f2bfh(lo[3]);
    r[4]=(short)f2bfh(hi[0]); r[5]=(short)f2bfh(hi[1]);
    r[6]=(short)f2bfh(hi[2]); r[7]=(short)f2bfh(hi[3]);
    return r;
}

// load 8 contiguous f32 and convert to a bf16 MFMA fragment (fallback path)
__device__ __forceinline__ bf16x8 load8f(const float* p){
    f32x4 lo = *(const f32x4*)p;
    f32x4 hi = *(const f32x4*)(p+4);
    return cvt8(lo, hi);
}

#define FENCE_LDS() do { \
    __builtin_amdgcn_sched_barrier(0); \
    asm volatile("s_waitcnt lgkmcnt(0)" ::: "memory"); \
    __builtin_amdgcn_sched_barrier(0); \
} while(0)

// ---------------------------------------------------------------------------
// Kernel 0: one-time f32 -> bf16 conversion of x and the four weight matrices.
// blocks 0..1023: x (2M elems). blocks 1024..1535: Wq/Wk/Wv/Wout (256K each).
// ---------------------------------------------------------------------------
__global__ __launch_bounds__(256) void cvt5_kernel(
    const float* __restrict__ x,  const float* __restrict__ wq,
    const float* __restrict__ wk, const float* __restrict__ wv,
    const float* __restrict__ wo,
    unsigned short* __restrict__ xb,  unsigned short* __restrict__ wqb,
    unsigned short* __restrict__ wkb, unsigned short* __restrict__ wvb,
    unsigned short* __restrict__ wob)
{
    int b = blockIdx.x;
    const float* src; unsigned short* dst; int base;
    if (b < 1024){ src = x; dst = xb; base = b; }
    else {
        int t  = (b - 1024) >> 7;
        base   = (b - 1024) & 127;
        src = (t==0) ? wq  : (t==1) ? wk  : (t==2) ? wv  : wo;
        dst = (t==0) ? wqb : (t==1) ? wkb : (t==2) ? wvb : wob;
    }
    size_t i = ((size_t)base*256 + threadIdx.x)*8;
    f32x4 lo = *(const f32x4*)(src + i);
    f32x4 hi = *(const f32x4*)(src + i + 4);
    *(bf16x8*)(dst + i) = cvt8(lo, hi);
}

// ---------------------------------------------------------------------------
// Kernel 1 (fast path): fused Q/K/V projections from pre-converted bf16.
// z selects W (0=Q,1=K,2=V); V written transposed Vt[outdim][seq].
// ---------------------------------------------------------------------------
__global__ __launch_bounds__(256) void proj_qkv_b_kernel(
    const unsigned short* __restrict__ xb,
    const unsigned short* __restrict__ Wqb, const float* __restrict__ bq,
    const unsigned short* __restrict__ Wkb, const float* __restrict__ bk,
    const unsigned short* __restrict__ Wvb, const float* __restrict__ bv,
    unsigned short* __restrict__ Qb, unsigned short* __restrict__ Kb,
    unsigned short* __restrict__ Vt)
{
    const int z = blockIdx.z;
    const unsigned short* W = (z==0) ? Wqb : ((z==1) ? Wkb : Wvb);
    const float* bb = (z==0) ? bq : ((z==1) ? bk : bv);
    const int wv  = threadIdx.x >> 6;
    const int l   = threadIdx.x & 63;
    const int g   = l >> 4;
    const int l15 = l & 15;
    const int r0  = blockIdx.x * 128 + wv * 32;
    const int c0  = blockIdx.y * 64;

    f32x4 acc[2][4];
    #pragma unroll
    for(int s=0;s<2;s++)
        #pragma unroll
        for(int d=0;d<4;d++) acc[s][d] = (f32x4){0.f,0.f,0.f,0.f};

    for(int kt=0; kt<DIM; kt+=32){
        bf16x8 a[2];
        #pragma unroll
        for(int s=0;s<2;s++)
            a[s] = *(const bf16x8*)(xb + (size_t)(r0+s*16+l15)*DIM + kt + g*8);
        #pragma unroll
        for(int d=0;d<4;d++){
            bf16x8 b = *(const bf16x8*)(W + (size_t)(c0+d*16+l15)*DIM + kt + g*8);
            #pragma unroll
            for(int s=0;s<2;s++)
                acc[s][d] = __builtin_amdgcn_mfma_f32_16x16x32_bf16(a[s], b, acc[s][d], 0,0,0);
        }
    }

    #pragma unroll
    for(int d=0;d<4;d++){
        float bias = bb[c0 + d*16 + l15];
        #pragma unroll
        for(int s=0;s<2;s++){
            if(z == 2){
                s16x4 pk;
                #pragma unroll
                for(int r=0;r<4;r++) pk[r] = (short)f2bfh(acc[s][d][r] + bias);
                *(s16x4*)(Vt + (size_t)(c0+d*16+l15)*SEQ + r0 + s*16 + g*4) = pk;
            } else {
                unsigned short* o = (z==0) ? Qb : Kb;
                #pragma unroll
                for(int r=0;r<4;r++)
                    o[(size_t)(r0+s*16+g*4+r)*DIM + c0 + d*16 + l15] = f2bfh(acc[s][d][r] + bias);
            }
        }
    }
}

// ---------------------------------------------------------------------------
// Kernel 1 (fallback, ws too small): round-1 proj with in-loop f32->bf16 cvt
// ---------------------------------------------------------------------------
__global__ __launch_bounds__(256) void proj_qkv_kernel(
    const float* __restrict__ x,
    const float* __restrict__ Wq, const float* __restrict__ bq,
    const float* __restrict__ Wk, const float* __restrict__ bk,
    const float* __restrict__ Wv, const float* __restrict__ bv,
    unsigned short* __restrict__ Qb, unsigned short* __restrict__ Kb,
    unsigned short* __restrict__ Vt)
{
    const int z = blockIdx.z;
    const float* W  = (z==0) ? Wq : ((z==1) ? Wk : Wv);
    const float* bb = (z==0) ? bq : ((z==1) ? bk : bv);
    const int wv  = threadIdx.x >> 6;
    const int l   = threadIdx.x & 63;
    const int g   = l >> 4;
    const int l15 = l & 15;
    const int r0  = blockIdx.x * 128 + wv * 32;
    const int c0  = blockIdx.y * 64;

    f32x4 acc[2][4];
    #pragma unroll
    for(int s=0;s<2;s++)
        #pragma unroll
        for(int d=0;d<4;d++) acc[s][d] = (f32x4){0.f,0.f,0.f,0.f};

    for(int kt=0; kt<DIM; kt+=32){
        bf16x8 a[2];
        #pragma unroll
        for(int s=0;s<2;s++)
            a[s] = load8f(x + (size_t)(r0+s*16+l15)*DIM + kt + g*8);
        #pragma unroll
        for(int d=0;d<4;d++){
            bf16x8 b = load8f(W + (size_t)(c0+d*16+l15)*DIM + kt + g*8);
            #pragma unroll
            for(int s=0;s<2;s++)
                acc[s][d] = __builtin_amdgcn_mfma_f32_16x16x32_bf16(a[s], b, acc[s][d], 0,0,0);
        }
    }

    #pragma unroll
    for(int d=0;d<4;d++){
        float bias = bb[c0 + d*16 + l15];
        #pragma unroll
        for(int s=0;s<2;s++){
            if(z == 2){
                s16x4 pk;
                #pragma unroll
                for(int r=0;r<4;r++) pk[r] = (short)f2bfh(acc[s][d][r] + bias);
                *(s16x4*)(Vt + (size_t)(c0+d*16+l15)*SEQ + r0 + s*16 + g*4) = pk;
            } else {
                unsigned short* o = (z==0) ? Qb : Kb;
                #pragma unroll
                for(int r=0;r<4;r++)
                    o[(size_t)(r0+s*16+g*4+r)*DIM + c0 + d*16 + l15] = f2bfh(acc[s][d][r] + bias);
            }
        }
    }
}

// ---------------------------------------------------------------------------
// Kernel 2: two-pass attention, in-block K-split for 4x occupancy.
// Block = 32 q-rows of one head; wave w handles keys [w*1024, (w+1)*1024).
// Pass A: per-wave raw-score row max -> exact cross-wave max merge via LDS.
// Pass B: p = fexp-fused(one FMA + clamp + cvt), P->LDS transpose (stride 68,
// conflict-free), PV + den-by-ones-MFMA; cross-wave f32 merge via LDS.
// ---------------------------------------------------------------------------
#define PSTRIDE 68
#define MBSTRIDE 41

__global__ __launch_bounds__(256, 4) void attn_kernel(
    const unsigned short* __restrict__ Qb,
    const unsigned short* __restrict__ Kb,
    const unsigned short* __restrict__ Vt,
    unsigned short* __restrict__ Ab,
    float k1f)   // GIST_A * scaling
{
    __shared__ __align__(16) unsigned char smem[3*64*MBSTRIDE*4 + 4*32*4];
    unsigned short* myplds = (unsigned short*)smem + (threadIdx.x >> 6) * (32*PSTRIDE);
    float* mbuf = (float*)smem;                          // [3][64][MBSTRIDE]
    float* mmax = (float*)(smem + 3*64*MBSTRIDE*4);      // [4][32]

    const int wv  = threadIdx.x >> 6;
    const int l   = threadIdx.x & 63;
    const int g   = l >> 4;
    const int l15 = l & 15;
    const int h   = blockIdx.y;
    const int r0  = blockIdx.x * 32;
    const int kb  = wv * (SEQ/4);

    // Q fragments for 32 rows x 64 dims (same for all 4 waves)
    bf16x8 aq[2][2];
    #pragma unroll
    for(int s=0;s<2;s++)
        #pragma unroll
        for(int kh=0;kh<2;kh++)
            aq[s][kh] = *(const bf16x8*)(Qb + (size_t)(r0+s*16+l15)*DIM + h*HD + kh*32 + g*8);

    // ---- pass A: per-wave partial raw max ----
    float mx[2][4];
    #pragma unroll
    for(int s=0;s<2;s++){ mx[s][0]=mx[s][1]=mx[s][2]=mx[s][3]=-3.0e38f; }

    for(int k0=kb; k0<kb+SEQ/4; k0+=64){
        #pragma unroll
        for(int ks=0;ks<4;ks++){
            const unsigned short* kp = Kb + (size_t)(k0+ks*16+l15)*DIM + h*HD + g*8;
            bf16x8 b0 = *(const bf16x8*)kp;
            bf16x8 b1 = *(const bf16x8*)(kp + 32);
            #pragma unroll
            for(int s=0;s<2;s++){
                f32x4 acc = (f32x4){0.f,0.f,0.f,0.f};
                acc = __builtin_amdgcn_mfma_f32_16x16x32_bf16(aq[s][0], b0, acc, 0,0,0);
                acc = __builtin_amdgcn_mfma_f32_16x16x32_bf16(aq[s][1], b1, acc, 0,0,0);
                #pragma unroll
                for(int r=0;r<4;r++) mx[s][r] = fmaxf(mx[s][r], acc[r]);
            }
        }
    }
    // reduce across the 16 lanes (columns) of each row group
    #pragma unroll
    for(int off=1; off<16; off<<=1)
        #pragma unroll
        for(int s=0;s<2;s++)
            #pragma unroll
            for(int r=0;r<4;r++)
                mx[s][r] = fmaxf(mx[s][r], __shfl_xor(mx[s][r], off, 64));

    // exact cross-wave max merge
    if(l15 == 0){
        #pragma unroll
        for(int s=0;s<2;s++)
            #pragma unroll
            for(int r=0;r<4;r++)
                mmax[wv*32 + s*16 + g*4 + r] = mx[s][r];
    }
    __syncthreads();
    // per-row fused-exp constant: c = GIST_B - k1f*m_raw  (t = k1f*s + c <= B)
    float crow[2][4];
    #pragma unroll
    for(int s=0;s<2;s++)
        #pragma unroll
        for(int r=0;r<4;r++){
            float m = mmax[0*32 + s*16 + g*4 + r];
            m = fmaxf(m, mmax[1*32 + s*16 + g*4 + r]);
            m = fmaxf(m, mmax[2*32 + s*16 + g*4 + r]);
            m = fmaxf(m, mmax[3*32 + s*16 + g*4 + r]);
            crow[s][r] = 1064986823.0f - k1f*m;
        }

    // ---- pass B ----
    f32x4 oacc[2][4];
    #pragma unroll
    for(int s=0;s<2;s++)
        #pragma unroll
        for(int d=0;d<4;d++) oacc[s][d] = (f32x4){0.f,0.f,0.f,0.f};
    f32x4 dacc[2];
    dacc[0] = (f32x4){0.f,0.f,0.f,0.f};
    dacc[1] = (f32x4){0.f,0.f,0.f,0.f};

    bf16x8 ones;
    #pragma unroll
    for(int j=0;j<8;j++) ones[j] = (short)0x3F80;   // bf16 1.0

    for(int k0=kb; k0<kb+SEQ/4; k0+=64){
        #pragma unroll
        for(int ks=0;ks<4;ks++){
            const unsigned short* kp = Kb + (size_t)(k0+ks*16+l15)*DIM + h*HD + g*8;
            bf16x8 b0 = *(const bf16x8*)kp;
            bf16x8 b1 = *(const bf16x8*)(kp + 32);
            #pragma unroll
            for(int s=0;s<2;s++){
                f32x4 acc = (f32x4){0.f,0.f,0.f,0.f};
                acc = __builtin_amdgcn_mfma_f32_16x16x32_bf16(aq[s][0], b0, acc, 0,0,0);
                acc = __builtin_amdgcn_mfma_f32_16x16x32_bf16(aq[s][1], b1, acc, 0,0,0);
                #pragma unroll
                for(int r=0;r<4;r++){
                    float t = fmaf(k1f, acc[r], crow[s][r]);
                    t = (t < 8388608.0f) ? 0.0f : t;      // underflow -> 0
                    float p = __int_as_float((int)t);
                    myplds[(s*16+g*4+r)*PSTRIDE + ks*16 + l15] = f2bfh(p);
                }
            }
        }
        FENCE_LDS();   // wave-synchronous: P writes visible to cross-lane reads

        #pragma unroll
        for(int ks2=0; ks2<2; ks2++){
            bf16x8 pa[2];
            #pragma unroll
            for(int s=0;s<2;s++)
                pa[s] = *(const bf16x8*)&myplds[(s*16+l15)*PSTRIDE + ks2*32 + g*8];
            // row-sum (denominator) via ones-fragment MFMA
            #pragma unroll
            for(int s=0;s<2;s++)
                dacc[s] = __builtin_amdgcn_mfma_f32_16x16x32_bf16(pa[s], ones, dacc[s], 0,0,0);
            #pragma unroll
            for(int d=0;d<4;d++){
                bf16x8 bv_ = *(const bf16x8*)(Vt + (size_t)(h*HD + d*16 + l15)*SEQ + k0 + ks2*32 + g*8);
                #pragma unroll
                for(int s=0;s<2;s++)
                    oacc[s][d] = __builtin_amdgcn_mfma_f32_16x16x32_bf16(pa[s], bv_, oacc[s][d], 0,0,0);
            }
        }
        FENCE_LDS();   // reads done before next iteration overwrites P
    }

    // ---- cross-wave merge of num/den (f32 adds, exact modulo reorder) ----
    __syncthreads();   // all waves done with plds region (aliased by mbuf)
    if(wv > 0){
        float* mb = mbuf + ((size_t)(wv-1)*64 + l)*MBSTRIDE;
        #pragma unroll
        for(int s=0;s<2;s++)
            #pragma unroll
            for(int d=0;d<4;d++)
                #pragma unroll
                for(int r=0;r<4;r++)
                    mb[(s*4+d)*4 + r] = oacc[s][d][r];
        #pragma unroll
        for(int s=0;s<2;s++)
            #pragma unroll
            for(int r=0;r<4;r++)
                mb[32 + s*4 + r] = dacc[s][r];
    }
    __syncthreads();
    if(wv == 0){
        #pragma unroll
        for(int w=0;w<3;w++){
            const float* mb = mbuf + ((size_t)w*64 + l)*MBSTRIDE;
            #pragma unroll
            for(int s=0;s<2;s++)
                #pragma unroll
                for(int d=0;d<4;d++)
                    #pragma unroll
                    for(int r=0;r<4;r++)
                        oacc[s][d][r] += mb[(s*4+d)*4 + r];
            #pragma unroll
            for(int s=0;s<2;s++)
                #pragma unroll
                for(int r=0;r<4;r++)
                    dacc[s][r] += mb[32 + s*4 + r];
        }
        #pragma unroll
        for(int s=0;s<2;s++){
            float inv[4];
            #pragma unroll
            for(int r=0;r<4;r++) inv[r] = 1.0f / dacc[s][r];
            #pragma unroll
            for(int d=0;d<4;d++)
                #pragma unroll
                for(int r=0;r<4;r++)
                    Ab[(size_t)(r0+s*16+g*4+r)*DIM + h*HD + d*16 + l15] =
                        f2bfh(oacc[s][d][r] * inv[r]);
        }
    }
}

// ---------------------------------------------------------------------------
// Kernel 3 (fast path): output projection from bf16 Wout. f32 output.
// ---------------------------------------------------------------------------
__global__ __launch_bounds__(256) void proj_out_b_kernel(
    const unsigned short* __restrict__ Ab,
    const unsigned short* __restrict__ Wob,
    float* __restrict__ out)
{
    const int wv  = threadIdx.x >> 6;
    const int l   = threadIdx.x & 63;
    const int g   = l >> 4;
    const int l15 = l & 15;
    const int r0  = blockIdx.x * 128 + wv * 32;
    const int c0  = blockIdx.y * 64;

    f32x4 acc[2][4];
    #pragma unroll
    for(int s=0;s<2;s++)
        #pragma unroll
        for(int d=0;d<4;d++) acc[s][d] = (f32x4){0.f,0.f,0.f,0.f};

    for(int kt=0; kt<DIM; kt+=32){
        bf16x8 a[2];
        #pragma unroll
        for(int s=0;s<2;s++)
            a[s] = *(const bf16x8*)(Ab + (size_t)(r0+s*16+l15)*DIM + kt + g*8);
        #pragma unroll
        for(int d=0;d<4;d++){
            bf16x8 b = *(const bf16x8*)(Wob + (size_t)(c0+d*16+l15)*DIM + kt + g*8);
            #pragma unroll
            for(int s=0;s<2;s++)
                acc[s][d] = __builtin_amdgcn_mfma_f32_16x16x32_bf16(a[s], b, acc[s][d], 0,0,0);
        }
    }

    #pragma unroll
    for(int s=0;s<2;s++)
        #pragma unroll
        for(int d=0;d<4;d++)
            #pragma unroll
            for(int r=0;r<4;r++)
                out[(size_t)(r0+s*16+g*4+r)*DIM + c0 + d*16 + l15] = acc[s][d][r];
}

// fallback out-proj (f32 Wout with in-loop cvt)
__global__ __launch_bounds__(256) void proj_out_kernel(
    const unsigned short* __restrict__ Ab,
    const float* __restrict__ Wout,
    float* __restrict__ out)
{
    const int wv  = threadIdx.x >> 6;
    const int l   = threadIdx.x & 63;
    const int g   = l >> 4;
    const int l15 = l & 15;
    const int r0  = blockIdx.x * 128 + wv * 32;
    const int c0  = blockIdx.y * 64;

    f32x4 acc[2][4];
    #pragma unroll
    for(int s=0;s<2;s++)
        #pragma unroll
        for(int d=0;d<4;d++) acc[s][d] = (f32x4){0.f,0.f,0.f,0.f};

    for(int kt=0; kt<DIM; kt+=32){
        bf16x8 a[2];
        #pragma unroll
        for(int s=0;s<2;s++)
            a[s] = *(const bf16x8*)(Ab + (size_t)(r0+s*16+l15)*DIM + kt + g*8);
        #pragma unroll
        for(int d=0;d<4;d++){
            bf16x8 b = load8f(Wout + (size_t)(c0+d*16+l15)*DIM + kt + g*8);
            #pragma unroll
            for(int s=0;s<2;s++)
                acc[s][d] = __builtin_amdgcn_mfma_f32_16x16x32_bf16(a[s], b, acc[s][d], 0,0,0);
        }
    }

    #pragma unroll
    for(int s=0;s<2;s++)
        #pragma unroll
        for(int d=0;d<4;d++)
            #pragma unroll
            for(int r=0;r<4;r++)
                out[(size_t)(r0+s*16+g*4+r)*DIM + c0 + d*16 + l15] = acc[s][d][r];
}

// ---------------------------------------------------------------------------
extern "C" void kernel_launch(void* const* d_in, const int* in_sizes, int n_in,
                              void* d_out, int out_size, void* d_ws, size_t ws_size,
                              hipStream_t stream)
{
    const float* x    = (const float*)d_in[0];
    const float* Wq   = (const float*)d_in[1];
    const float* bq   = (const float*)d_in[2];
    const float* Wk   = (const float*)d_in[3];
    const float* bk   = (const float*)d_in[4];
    const float* Wv   = (const float*)d_in[5];
    const float* bv   = (const float*)d_in[6];
    const float* Wout = (const float*)d_in[7];
    float* out = (float*)d_out;

    unsigned short* Qb = (unsigned short*)d_ws;          // [SEQ][DIM] bf16
    unsigned short* Kb = Qb + (size_t)SEQ*DIM;           // [SEQ][DIM] bf16
    unsigned short* Vt = Kb + (size_t)SEQ*DIM;           // [DIM][SEQ] bf16 (transposed)
    unsigned short* Ab = Vt + (size_t)SEQ*DIM;           // [SEQ][DIM] bf16
    unsigned short* xb = Ab + (size_t)SEQ*DIM;           // [SEQ][DIM] bf16
    unsigned short* Wqb = xb  + (size_t)SEQ*DIM;         // [DIM][DIM] bf16
    unsigned short* Wkb = Wqb + (size_t)DIM*DIM;
    unsigned short* Wvb = Wkb + (size_t)DIM*DIM;
    unsigned short* Wob = Wvb + (size_t)DIM*DIM;
    const size_t needed = ((size_t)SEQ*DIM*5 + (size_t)DIM*DIM*4) * 2;

    // quake fast inverse sqrt of HEAD_DIM, replicating the numpy f32 ops
    float xx = 64.0f;
    float x2 = xx * 0.5f;
    int ii; memcpy(&ii, &xx, 4);
    ii = 1597463007 - (ii >> 1);
    float y; memcpy(&y, &ii, 4);
    y = y * (1.5f - x2 * y * y);
    const float scaling = y;
    const float k1f = 12102203.17133801f * scaling;   // GIST_A * scaling (f32)

    if(ws_size >= needed){
        cvt5_kernel<<<dim3(1536), 256, 0, stream>>>(
            x, Wq, Wk, Wv, Wout, xb, Wqb, Wkb, Wvb, Wob);
        proj_qkv_b_kernel<<<dim3(SEQ/128, DIM/64, 3), 256, 0, stream>>>(
            xb, Wqb, bq, Wkb, bk, Wvb, bv, Qb, Kb, Vt);
        attn_kernel<<<dim3(SEQ/32, NH), 256, 0, stream>>>(Qb, Kb, Vt, Ab, k1f);
        proj_out_b_kernel<<<dim3(SEQ/128, DIM/64), 256, 0, stream>>>(Ab, Wob, out);
    } else {
        proj_qkv_kernel<<<dim3(SEQ/128, DIM/64, 3), 256, 0, stream>>>(
            x, Wq, bq, Wk, bk, Wv, bv, Qb, Kb, Vt);
        attn_kernel<<<dim3(SEQ/32, NH), 256, 0, stream>>>(Qb, Kb, Vt, Ab, k1f);
        proj_out_kernel<<<dim3(SEQ/128, DIM/64), 256, 0, stream>>>(Ab, Wout, out);
    }
}